// Round 1
// baseline (553.174 us; speedup 1.0000x reference)
//
#include <hip/hip_runtime.h>

namespace {
constexpr int T_N = 262144;   // number of times
constexpr int S_N = 512;      // weight columns
constexpr int K_N = 258;      // NUM_KNOTS + DEGREE - 1 (basis count / weight rows)
constexpr int NK  = 262;      // NUM_KNOTS + 2*DEGREE (knot vector length)
constexpr int ROWS_PER_WAVE = 32;
}

// Pre-kernel: per-row sums of weights (258 rows x 512 cols) -> d_ws.
// One wave per row; butterfly reduce over 64 lanes.
__global__ void wsum_kernel(const float* __restrict__ W, float* __restrict__ wsum) {
    const int row  = blockIdx.x * 4 + (threadIdx.x >> 6);
    const int lane = threadIdx.x & 63;
    if (row >= K_N) return;
    const float* wr = W + (size_t)row * S_N;
    float s = 0.f;
#pragma unroll
    for (int c = 0; c < S_N / 64; ++c) s += wr[lane + c * 64];
#pragma unroll
    for (int off = 32; off > 0; off >>= 1) s += __shfl_xor(s, off, 64);
    if (lane == 0) wsum[row] = s;
}

// Main kernel: one wave per output row, ROWS_PER_WAVE consecutive rows per wave.
// Weight rows for the current span cached in registers (spans change ~every 1024 rows).
__global__ __launch_bounds__(256) void bspline_kernel(
    const float* __restrict__ times,
    const float* __restrict__ W,
    const float* __restrict__ knots,
    const float* __restrict__ wsum,
    float* __restrict__ out,
    float* __restrict__ out_sum)
{
    __shared__ float sk[NK];
    for (int i = threadIdx.x; i < NK; i += 256) sk[i] = knots[i];
    __syncthreads();

    const float k3    = sk[3];
    const float kend  = sk[NK - 4];               // knots[258] == times[-1]
    const float inv_h = 255.0f / (kend - k3);     // interior knots are linspace

    const int wave = (int)((blockIdx.x * 256u + threadIdx.x) >> 6);
    const int lane = threadIdx.x & 63;
    const int row0 = wave * ROWS_PER_WAVE;

    const int colA = lane * 4;
    const int colB = colA + 256;

    int span = -1;
    float4 wA0, wA1, wA2, wA3, wB0, wB1, wB2, wB3;
    float ws0 = 0.f, ws1 = 0.f, ws2 = 0.f, ws3 = 0.f;

    for (int r = 0; r < ROWS_PER_WAVE; ++r) {
        const int row = row0 + r;
        const float t = times[row];               // wave-uniform (all lanes same row)
        float* op = out + (size_t)row * S_N;

        // Reference's half-open degree-0 indicator: t == last knot -> all-zero row.
        if (t >= kend) {
            const float4 z = make_float4(0.f, 0.f, 0.f, 0.f);
            *(float4*)(op + colA) = z;
            *(float4*)(op + colB) = z;
            if (lane == 0) out_sum[row] = 0.f;
            continue;
        }

        // Span i: knots[i] <= t < knots[i+1], i in [3, 257].
        int i = 3 + (int)((t - k3) * inv_h);
        i = i < 3 ? 3 : (i > 257 ? 257 : i);
        while (t <  sk[i])     --i;   // fixups: 0-1 steps (knots ~uniform)
        while (t >= sk[i + 1]) ++i;

        // Cox-de Boor (NURBS A2.2): N0..N3 = B_{i-3..i}(t).
        // All denominators contain the non-empty [k_i, k_{i+1}) -> nonzero,
        // matching the reference's drop-zero-denominator convention.
        float N0, N1, N2, N3;
        {
            const float left1  = t - sk[i];
            const float right1 = sk[i + 1] - t;
            const float left2  = t - sk[i - 1];
            const float right2 = sk[i + 2] - t;
            const float left3  = t - sk[i - 2];
            const float right3 = sk[i + 3] - t;
            float temp, saved;
            // j = 1
            temp = 1.0f / (right1 + left1);
            N0 = right1 * temp;
            N1 = left1 * temp;
            // j = 2
            temp = N0 / (right1 + left2);
            N0 = right1 * temp;
            saved = left2 * temp;
            temp = N1 / (right2 + left1);
            N1 = saved + right2 * temp;
            N2 = left1 * temp;
            // j = 3
            temp = N0 / (right1 + left3);
            N0 = right1 * temp;
            saved = left3 * temp;
            temp = N1 / (right2 + left2);
            N1 = saved + right2 * temp;
            saved = left2 * temp;
            temp = N2 / (right3 + left1);
            N2 = saved + right3 * temp;
            N3 = left1 * temp;
        }

        // Refresh register-cached weight rows when span changes (wave-uniform branch).
        if (i != span) {
            span = i;
            const float* wp = W + (size_t)(i - 3) * S_N;
            wA0 = *(const float4*)(wp + colA);
            wB0 = *(const float4*)(wp + colB);
            wA1 = *(const float4*)(wp + S_N + colA);
            wB1 = *(const float4*)(wp + S_N + colB);
            wA2 = *(const float4*)(wp + 2 * S_N + colA);
            wB2 = *(const float4*)(wp + 2 * S_N + colB);
            wA3 = *(const float4*)(wp + 3 * S_N + colA);
            wB3 = *(const float4*)(wp + 3 * S_N + colB);
            ws0 = wsum[i - 3]; ws1 = wsum[i - 2]; ws2 = wsum[i - 1]; ws3 = wsum[i];
        }

        float4 oa, ob;
        oa.x = N0 * wA0.x + N1 * wA1.x + N2 * wA2.x + N3 * wA3.x;
        oa.y = N0 * wA0.y + N1 * wA1.y + N2 * wA2.y + N3 * wA3.y;
        oa.z = N0 * wA0.z + N1 * wA1.z + N2 * wA2.z + N3 * wA3.z;
        oa.w = N0 * wA0.w + N1 * wA1.w + N2 * wA2.w + N3 * wA3.w;
        ob.x = N0 * wB0.x + N1 * wB1.x + N2 * wB2.x + N3 * wB3.x;
        ob.y = N0 * wB0.y + N1 * wB1.y + N2 * wB2.y + N3 * wB3.y;
        ob.z = N0 * wB0.z + N1 * wB1.z + N2 * wB2.z + N3 * wB3.z;
        ob.w = N0 * wB0.w + N1 * wB1.w + N2 * wB2.w + N3 * wB3.w;

        *(float4*)(op + colA) = oa;
        *(float4*)(op + colB) = ob;
        if (lane == 0)
            out_sum[row] = N0 * ws0 + N1 * ws1 + N2 * ws2 + N3 * ws3;
    }
}

extern "C" void kernel_launch(void* const* d_in, const int* in_sizes, int n_in,
                              void* d_out, int out_size, void* d_ws, size_t ws_size,
                              hipStream_t stream) {
    const float* times = (const float*)d_in[0];
    const float* W     = (const float*)d_in[1];
    const float* knots = (const float*)d_in[2];
    float* out     = (float*)d_out;
    float* out_sum = out + (size_t)T_N * S_N;   // outputs concatenated flat
    float* wsum    = (float*)d_ws;              // 258 floats of scratch

    wsum_kernel<<<(K_N + 3) / 4, 256, 0, stream>>>(W, wsum);

    const int nwaves = T_N / ROWS_PER_WAVE;     // 8192 waves
    bspline_kernel<<<nwaves / 4, 256, 0, stream>>>(times, W, knots, wsum, out, out_sum);
}